// Round 1
// baseline (1143.194 us; speedup 1.0000x reference)
//
#include <hip/hip_runtime.h>

#define N_NODES 100000
#define D_FEAT  64
#define N_EDGES 1600000

// One 64-lane wave per edge; lane = feature index.
// src/dst/ew reads are wave-uniform (broadcast, 1 transaction);
// row gather/scatter are 256B contiguous -> fully coalesced.
__global__ void spmm_atomic(const float* __restrict__ X,
                            const int*   __restrict__ src,
                            const int*   __restrict__ dst,
                            const float* __restrict__ ew,
                            float*       __restrict__ out,
                            int n_edges) {
    long long tid = (long long)blockIdx.x * blockDim.x + threadIdx.x;
    int e    = (int)(tid >> 6);
    int lane = (int)(tid & 63);
    if (e >= n_edges) return;
    int   s = src[e];
    int   d = dst[e];
    float w = ew[e];
    float v = X[(size_t)s * D_FEAT + lane] * w;
    atomicAdd(&out[(size_t)d * D_FEAT + lane], v);
}

// out = 0.25*(X + h1 + h2 + h3), float4-vectorized
__global__ void final_avg(const float* __restrict__ X,
                          const float* __restrict__ h1,
                          const float* __restrict__ h2,
                          const float* __restrict__ h3,
                          float* __restrict__ out,
                          int n4) {
    int i = blockIdx.x * blockDim.x + threadIdx.x;
    if (i >= n4) return;
    const float4* X4  = (const float4*)X;
    const float4* a4  = (const float4*)h1;
    const float4* b4  = (const float4*)h2;
    const float4* c4  = (const float4*)h3;
    float4 x = X4[i], a = a4[i], b = b4[i], c = c4[i];
    float4 r;
    r.x = 0.25f * (x.x + a.x + b.x + c.x);
    r.y = 0.25f * (x.y + a.y + b.y + c.y);
    r.z = 0.25f * (x.z + a.z + b.z + c.z);
    r.w = 0.25f * (x.w + a.w + b.w + c.w);
    ((float4*)out)[i] = r;
}

extern "C" void kernel_launch(void* const* d_in, const int* in_sizes, int n_in,
                              void* d_out, int out_size, void* d_ws, size_t ws_size,
                              hipStream_t stream) {
    const float* X   = (const float*)d_in[0];
    const int*   src = (const int*)  d_in[1];
    const int*   dst = (const int*)  d_in[2];
    const float* ew  = (const float*)d_in[3];
    float* out = (float*)d_out;

    const size_t feat_elems = (size_t)N_NODES * D_FEAT;
    float* h1 = (float*)d_ws;
    float* h2 = h1 + feat_elems;
    float* h3 = h2 + feat_elems;

    // zero the three intermediate feature buffers (ws is poisoned 0xAA)
    hipMemsetAsync(h1, 0, 3 * feat_elems * sizeof(float), stream);

    const long long spmm_threads = (long long)N_EDGES * 64;
    dim3 block(256);
    dim3 grid((unsigned)((spmm_threads + 255) / 256));

    spmm_atomic<<<grid, block, 0, stream>>>(X,  src, dst, ew, h1, N_EDGES);
    spmm_atomic<<<grid, block, 0, stream>>>(h1, src, dst, ew, h2, N_EDGES);
    spmm_atomic<<<grid, block, 0, stream>>>(h2, src, dst, ew, h3, N_EDGES);

    const int n4 = (int)(feat_elems / 4);
    final_avg<<<(n4 + 255) / 256, 256, 0, stream>>>(X, h1, h2, h3, out, n4);
}

// Round 2
// 588.727 us; speedup vs baseline: 1.9418x; 1.9418x over previous
//
#include <hip/hip_runtime.h>

#define N_NODES 100000
#define D_FEAT  64
#define N_EDGES 1600000
#define SCAN_NB ((N_NODES + 255) / 256)   // 391

// ---------------- CSR build ----------------

__global__ void histogram_dst(const int* __restrict__ dst, int* __restrict__ deg) {
    int i = blockIdx.x * blockDim.x + threadIdx.x;
    int stride = gridDim.x * blockDim.x;
    for (; i < N_EDGES; i += stride)
        atomicAdd(&deg[dst[i]], 1);
}

// per-256-block exclusive scan; blockSums[b] = block total
__global__ void scan_blocks(const int* __restrict__ deg, int* __restrict__ ex,
                            int* __restrict__ blockSums) {
    __shared__ int tmp[256];
    int gid = blockIdx.x * 256 + threadIdx.x;
    int v = (gid < N_NODES) ? deg[gid] : 0;
    tmp[threadIdx.x] = v;
    __syncthreads();
    for (int off = 1; off < 256; off <<= 1) {
        int t = (threadIdx.x >= off) ? tmp[threadIdx.x - off] : 0;
        __syncthreads();
        tmp[threadIdx.x] += t;
        __syncthreads();
    }
    int incl = tmp[threadIdx.x];
    if (gid < N_NODES) ex[gid] = incl - v;
    if (threadIdx.x == 255) blockSums[blockIdx.x] = incl;
}

// exclusive scan of the 391 block sums (tiny; single thread is fine)
__global__ void scan_sums(int* __restrict__ blockSums) {
    if (threadIdx.x == 0 && blockIdx.x == 0) {
        int run = 0;
        for (int b = 0; b < SCAN_NB; ++b) {
            int v = blockSums[b];
            blockSums[b] = run;
            run += v;
        }
    }
}

// row_ptr[i] = ex[i] + blockSums[i/256]; also init fill cursor
__global__ void add_offsets(const int* __restrict__ ex, const int* __restrict__ blockSums,
                            int* __restrict__ row_ptr, int* __restrict__ fill) {
    int gid = blockIdx.x * 256 + threadIdx.x;
    if (gid < N_NODES) {
        int v = ex[gid] + blockSums[blockIdx.x];
        row_ptr[gid] = v;
        fill[gid] = v;
    }
    if (gid == 0) row_ptr[N_NODES] = N_EDGES;
}

// bucket-scatter edges into dst-grouped order; packed (src, weight) 8B
__global__ void scatter_edges(const int* __restrict__ src, const int* __restrict__ dst,
                              const float* __restrict__ ew, int* __restrict__ fill,
                              int2* __restrict__ edges) {
    int i = blockIdx.x * blockDim.x + threadIdx.x;
    int stride = gridDim.x * blockDim.x;
    for (; i < N_EDGES; i += stride) {
        int d = dst[i];
        int p = atomicAdd(&fill[d], 1);
        int2 e;
        e.x = src[i];
        e.y = __float_as_int(ew[i]);
        edges[p] = e;
    }
}

// ---------------- pull SpMM ----------------
// One 64-lane wave per destination node; lane = feature index.
// MODE 0: out = X_row + h   (write h)     [layer 1]
// MODE 1: out += h          (write h)     [layer 2]
// MODE 2: out = (out+h)/4   (skip h)      [layer 3]
template <int MODE>
__global__ void spmm_pull(const float* __restrict__ hprev,
                          const int* __restrict__ row_ptr,
                          const int2* __restrict__ edges,
                          float* __restrict__ hout,
                          float* __restrict__ acc,
                          const float* __restrict__ X) {
    int node = blockIdx.x * (blockDim.x >> 6) + (threadIdx.x >> 6);
    int lane = threadIdx.x & 63;
    if (node >= N_NODES) return;

    int beg = row_ptr[node];
    int end = row_ptr[node + 1];

    float a = 0.0f;
    for (int base = beg; base < end; base += 64) {
        int n = end - base;
        if (n > 64) n = 64;
        int s = 0;
        float w = 0.0f;
        if (lane < n) {
            int2 e = edges[base + lane];
            s = e.x;
            w = __int_as_float(e.y);
        }
        for (int j = 0; j < n; ++j) {
            int sj = __shfl(s, j);
            float wj = __shfl(w, j);
            a += hprev[(size_t)sj * D_FEAT + lane] * wj;
        }
    }

    size_t idx = (size_t)node * D_FEAT + lane;
    if (MODE == 0) {
        hout[idx] = a;
        acc[idx] = X[idx] + a;
    } else if (MODE == 1) {
        hout[idx] = a;
        acc[idx] += a;
    } else {
        acc[idx] = (acc[idx] + a) * 0.25f;
    }
}

extern "C" void kernel_launch(void* const* d_in, const int* in_sizes, int n_in,
                              void* d_out, int out_size, void* d_ws, size_t ws_size,
                              hipStream_t stream) {
    const float* X   = (const float*)d_in[0];
    const int*   src = (const int*)  d_in[1];
    const int*   dst = (const int*)  d_in[2];
    const float* ew  = (const float*)d_in[3];
    float* out = (float*)d_out;

    const size_t feat = (size_t)N_NODES * D_FEAT;   // 6.4M floats

    // workspace layout (all 8B-aligned sizes)
    char* p = (char*)d_ws;
    float* hA      = (float*)p;                 p += feat * sizeof(float);       // 25.6 MB
    float* hB      = (float*)p;                 p += feat * sizeof(float);       // 25.6 MB
    int2*  edges   = (int2*)p;                  p += (size_t)N_EDGES * 8;        // 12.8 MB
    int*   deg     = (int*)p;                   p += (size_t)N_NODES * 4;
    int*   ex      = (int*)p;                   p += (size_t)N_NODES * 4;
    int*   row_ptr = (int*)p;                   p += ((size_t)N_NODES + 2) * 4;
    int*   fill    = (int*)p;                   p += (size_t)N_NODES * 4;
    int*   bsums   = (int*)p;                   p += (size_t)SCAN_NB * 4;

    // zero degree histogram (ws is poisoned 0xAA)
    hipMemsetAsync(deg, 0, (size_t)N_NODES * sizeof(int), stream);

    // --- CSR build (grouped by dst) ---
    histogram_dst<<<1024, 256, 0, stream>>>(dst, deg);
    scan_blocks<<<SCAN_NB, 256, 0, stream>>>(deg, ex, bsums);
    scan_sums<<<1, 64, 0, stream>>>(bsums);
    add_offsets<<<SCAN_NB, 256, 0, stream>>>(ex, bsums, row_ptr, fill);
    scatter_edges<<<1024, 256, 0, stream>>>(src, dst, ew, fill, edges);

    // --- 3 pull-SpMM layers, layer-sum fused into d_out ---
    const int waves_per_block = 4;               // block = 256
    const int nblk = (N_NODES + waves_per_block - 1) / waves_per_block;
    spmm_pull<0><<<nblk, 256, 0, stream>>>(X,  row_ptr, edges, hA, out, X);
    spmm_pull<1><<<nblk, 256, 0, stream>>>(hA, row_ptr, edges, hB, out, X);
    spmm_pull<2><<<nblk, 256, 0, stream>>>(hB, row_ptr, edges, (float*)nullptr, out, X);
}